// Round 1
// baseline (532.893 us; speedup 1.0000x reference)
//
#include <hip/hip_runtime.h>
#include <hip/hip_bf16.h>

// ---------------------------------------------------------------------------
// Bn_bin_conv_pool: BN(batch stats) -> sign -> conv1d(K=7,pad3) -> *alpha ->
// maxpool2.  Reformulated as bf16 MFMA GEMM with K = Cin*K = 448.
// N=64, Cin=64, L=8192, Cout=128, K=7, Lout=4096.
// ---------------------------------------------------------------------------

#define N_S   64
#define C_IN  64
#define L_IN  8192
#define C_OUT 128
#define KW    7
#define L_OUT 4096
#define KDIM  448          // C_IN * KW, ordering t = k*64 + c
#define LT    64           // L-tile per workgroup
#define PROWS 70           // LT + KW - 1
#define RS    72           // LDS row stride (bf16 elems): 2-way-conflict-free

typedef float  fx4   __attribute__((ext_vector_type(4)));
typedef short  s16x8 __attribute__((ext_vector_type(8)));
typedef __bf16 bfx8  __attribute__((ext_vector_type(8)));

// --- SFINAE dual-path MFMA wrapper: tolerates either builtin signature -----
template <typename V> struct OtherFrag          { typedef bfx8  type; };
template <>           struct OtherFrag<bfx8>    { typedef s16x8 type; };

template <typename V>
static __device__ inline auto mfma_sel(V a, V b, fx4 c, int)
    -> decltype(__builtin_amdgcn_mfma_f32_16x16x32_bf16(a, b, c, 0, 0, 0)) {
  return __builtin_amdgcn_mfma_f32_16x16x32_bf16(a, b, c, 0, 0, 0);
}
template <typename V>
static __device__ inline fx4 mfma_sel(V a, V b, fx4 c, long) {
  typedef typename OtherFrag<V>::type O;
  return __builtin_amdgcn_mfma_f32_16x16x32_bf16(
      __builtin_bit_cast(O, a), __builtin_bit_cast(O, b), c, 0, 0, 0);
}
static __device__ inline fx4 mfma_bf16(s16x8 a, s16x8 b, fx4 c) {
  return mfma_sel(a, b, c, 0);
}

// --- Kernel 1: per-channel partial sums (fp64) -----------------------------
// grid (64 channels, 8 sample-groups) x 256 thr; each block: 8 samples.
__global__ __launch_bounds__(256)
void bnstats_kernel(const float* __restrict__ x_in, double* __restrict__ partials) {
  const int c = blockIdx.x, g = blockIdx.y, tid = threadIdx.x;
  double sum = 0.0, sq = 0.0;
  for (int ns = 0; ns < 8; ++ns) {
    const float4* b4 =
        (const float4*)(x_in + ((size_t)((g * 8 + ns) * C_IN + c) << 13));
#pragma unroll
    for (int j = 0; j < 8; ++j) {
      float4 v = b4[j * 256 + tid];
      double dx = v.x, dy = v.y, dz = v.z, dw = v.w;
      sum += dx + dy + dz + dw;
      sq  += dx * dx + dy * dy + dz * dz + dw * dw;
    }
  }
  for (int off = 32; off > 0; off >>= 1) {
    sum += __shfl_down(sum, off);
    sq  += __shfl_down(sq,  off);
  }
  __shared__ double sd[8];
  const int wv = tid >> 6;
  if ((tid & 63) == 0) { sd[wv * 2] = sum; sd[wv * 2 + 1] = sq; }
  __syncthreads();
  if (tid == 0) {
    double S = sd[0] + sd[2] + sd[4] + sd[6];
    double Q = sd[1] + sd[3] + sd[5] + sd[7];
    partials[(c * 8 + g) * 2]     = S;
    partials[(c * 8 + g) * 2 + 1] = Q;
  }
}

// --- Kernel 2: finalize mean_f / s_f per channel ---------------------------
__global__ void bnreduce_kernel(const double* __restrict__ partials,
                                float* __restrict__ meanArr,
                                float* __restrict__ sArr) {
  const int c = threadIdx.x;
  if (c < C_IN) {
    double S = 0.0, Q = 0.0;
    for (int g = 0; g < 8; ++g) {
      S += partials[(c * 8 + g) * 2];
      Q += partials[(c * 8 + g) * 2 + 1];
    }
    const double NL = (double)N_S * (double)L_IN;  // 524288
    double mean_d = S / NL;
    float  mean_f = (float)mean_d;
    // var as reference computes it: E[(I - mean_f)^2], in fp64
    double var_d = Q / NL - 2.0 * (double)mean_f * mean_d +
                   (double)mean_f * (double)mean_f;
    float var_f = (float)var_d;
    float vpe   = __fadd_rn(var_f, 1e-5f);          // fp32 add, like ref
    float s_f   = (float)(1.0 / sqrt((double)vpe)); // correctly-rounded rsqrt
    meanArr[c] = mean_f;
    sArr[c]    = s_f;
  }
}

// --- Kernel 3: repack W [o][c][k] fp32 -> Wr [o][t=k*64+c] bf16 ------------
__global__ __launch_bounds__(256)
void wrepack_kernel(const float* __restrict__ W, unsigned short* __restrict__ Wr) {
  const int f = blockIdx.x * 256 + threadIdx.x;
  if (f < C_OUT * KDIM) {
    const int o = f / KDIM, rem = f - o * KDIM;
    const int c = rem / KW, k = rem - c * KW;
    unsigned int u = __builtin_bit_cast(unsigned int, W[f]);
    u += 0x7FFFu + ((u >> 16) & 1u);  // round-to-nearest-even to bf16
    Wr[o * KDIM + k * C_IN + c] = (unsigned short)(u >> 16);
  }
}

// --- Kernel 4: binarize + conv (MFMA GEMM) + alpha + maxpool ---------------
// grid (128 L-tiles, 64 samples) x 256 thr (4 waves).
// Wave tile: 64 o x 32 l; WG tile: 128 o x 64 l.
__global__ __launch_bounds__(256)
void bconv_kernel(const float* __restrict__ x_in,
                  const float* __restrict__ gamma,
                  const float* __restrict__ beta,
                  const float* __restrict__ alpha,
                  const float* __restrict__ meanArr,
                  const float* __restrict__ sArr,
                  const unsigned short* __restrict__ Wr,
                  float* __restrict__ out) {
  const int tile = blockIdx.x;        // 0..127
  const int n    = blockIdx.y;        // 0..63
  const int l0   = tile * LT;
  const int tid  = threadIdx.x;

  __shared__ __align__(16) unsigned short lds_xb[PROWS * RS];

  // ---- stage binarized tile into LDS: lds_xb[p][c], p = l - l0 + 3 ----
  {
    const int c = tid >> 2, sub = tid & 3;
    const float m = meanArr[c], s = sArr[c], g = gamma[c], b = beta[c];
    const float* xc = x_in + ((size_t)(n * C_IN + c) << 13);
#pragma unroll
    for (int i = 0; i < 18; ++i) {
      const int p = sub * 18 + i;
      if (p < PROWS) {
        const int l = l0 + p - 3;
        unsigned short v = 0;  // zero padding outside [0, L)
        if (l >= 0 && l < L_IN) {
          // replicate reference fp32 rounding exactly: (((I-m)*s)*g)+b
          float x = __fadd_rn(__fmul_rn(__fmul_rn(__fsub_rn(xc[l], m), s), g), b);
          v = (x >= 0.0f) ? (unsigned short)0x3F80 : (unsigned short)0xBF80;
        }
        lds_xb[p * RS + c] = v;
      }
    }
  }
  __syncthreads();

  // ---- MFMA main loop ----
  const int lane = tid & 63, w = tid >> 6;
  const int n16 = lane & 15, quad = lane >> 4;
  const int obase = (w & 1) * 64;        // o-half of this wave
  const int lwave = (w >> 1) * 32;       // l-half of this wave

  fx4 acc[4][2];
#pragma unroll
  for (int ob = 0; ob < 4; ++ob)
#pragma unroll
    for (int lb = 0; lb < 2; ++lb)
      acc[ob][lb] = (fx4){0.f, 0.f, 0.f, 0.f};

  const unsigned short* arow = Wr + (obase + n16) * KDIM + quad * 8;

#pragma unroll
  for (int ks = 0; ks < 14; ++ks) {
    const int k  = ks >> 1;
    const int c0 = (ks & 1) * 32;
    s16x8 afr[4];
#pragma unroll
    for (int ob = 0; ob < 4; ++ob)
      afr[ob] = *(const s16x8*)(arow + ob * 16 * KDIM + ks * 32);
    s16x8 bfr[2];
#pragma unroll
    for (int lb = 0; lb < 2; ++lb) {
      const int p = lwave + lb * 16 + n16 + k;
      bfr[lb] = *(const s16x8*)(&lds_xb[p * RS + c0 + quad * 8]);
    }
#pragma unroll
    for (int ob = 0; ob < 4; ++ob)
#pragma unroll
      for (int lb = 0; lb < 2; ++lb)
        acc[ob][lb] = mfma_bf16(afr[ob], bfr[lb], acc[ob][lb]);
  }

  // ---- epilogue: maxpool(2) across lane pairs, *alpha, store ----
  const size_t outbase = (size_t)n * C_OUT * L_OUT;
#pragma unroll
  for (int ob = 0; ob < 4; ++ob) {
#pragma unroll
    for (int lb = 0; lb < 2; ++lb) {
      const int l_local = lwave + lb * 16 + n16;
#pragma unroll
      for (int r = 0; r < 4; ++r) {
        const int o = obase + ob * 16 + quad * 4 + r;
        float v  = acc[ob][lb][r];
        float pv = __shfl_xor(v, 1);
        float mx = fmaxf(v, pv);
        if ((n16 & 1) == 0) {
          out[outbase + (size_t)o * L_OUT + ((l0 + l_local) >> 1)] =
              mx * alpha[o];
        }
      }
    }
  }
}

// ---------------------------------------------------------------------------
extern "C" void kernel_launch(void* const* d_in, const int* in_sizes, int n_in,
                              void* d_out, int out_size, void* d_ws, size_t ws_size,
                              hipStream_t stream) {
  const float* x_in  = (const float*)d_in[0];  // I     [64,64,8192]
  const float* gamma = (const float*)d_in[1];  // [64]
  const float* beta  = (const float*)d_in[2];  // [64]
  const float* W     = (const float*)d_in[3];  // [128,64,7]
  const float* alpha = (const float*)d_in[4];  // [128,1]
  float* out = (float*)d_out;                  // [64,128,4096]

  // workspace layout
  double*         partials = (double*)d_ws;                       // 8192 B
  float*          meanArr  = (float*)((char*)d_ws + 8192);        // 256 B
  float*          sArr     = meanArr + 64;                        // 256 B
  unsigned short* Wr       = (unsigned short*)((char*)d_ws + 16384); // 114688 B

  bnstats_kernel<<<dim3(64, 8), 256, 0, stream>>>(x_in, partials);
  wrepack_kernel<<<(C_OUT * KDIM + 255) / 256, 256, 0, stream>>>(W, Wr);
  bnreduce_kernel<<<1, 64, 0, stream>>>(partials, meanArr, sArr);
  bconv_kernel<<<dim3(128, 64), 256, 0, stream>>>(
      x_in, gamma, beta, alpha, meanArr, sArr, Wr, out);
}

// Round 2
// 516.589 us; speedup vs baseline: 1.0316x; 1.0316x over previous
//
#include <hip/hip_runtime.h>
#include <hip/hip_bf16.h>

// ---------------------------------------------------------------------------
// Bn_bin_conv_pool: BN(batch stats) -> sign -> conv1d(K=7,pad3) -> *alpha ->
// maxpool2.  bf16 MFMA GEMM with K = Cin*KW = 448.
// v2: separate binarize+transpose kernel -> global xbt[n][p=l+3][c] (bf16),
//     bconv has NO LDS / NO barriers: A,B fragments loaded straight from
//     global (L1/L2-hot), 64o x 64l per wave, 128o x 128l per block.
// ---------------------------------------------------------------------------

#define N_S   64
#define C_IN  64
#define L_IN  8192
#define C_OUT 128
#define KW    7
#define L_OUT 4096
#define KDIM  448          // C_IN * KW, ordering t = k*64 + c
#define XROWS 8200         // padded rows per sample (p = l+3, valid 3..8194)

typedef float  fx4   __attribute__((ext_vector_type(4)));
typedef short  s16x8 __attribute__((ext_vector_type(8)));
typedef __bf16 bfx8  __attribute__((ext_vector_type(8)));

// --- SFINAE dual-path MFMA wrapper: tolerates either builtin signature -----
template <typename V> struct OtherFrag          { typedef bfx8  type; };
template <>           struct OtherFrag<bfx8>    { typedef s16x8 type; };

template <typename V>
static __device__ inline auto mfma_sel(V a, V b, fx4 c, int)
    -> decltype(__builtin_amdgcn_mfma_f32_16x16x32_bf16(a, b, c, 0, 0, 0)) {
  return __builtin_amdgcn_mfma_f32_16x16x32_bf16(a, b, c, 0, 0, 0);
}
template <typename V>
static __device__ inline fx4 mfma_sel(V a, V b, fx4 c, long) {
  typedef typename OtherFrag<V>::type O;
  return __builtin_amdgcn_mfma_f32_16x16x32_bf16(
      __builtin_bit_cast(O, a), __builtin_bit_cast(O, b), c, 0, 0, 0);
}
static __device__ inline fx4 mfma_bf16(s16x8 a, s16x8 b, fx4 c) {
  return mfma_sel(a, b, c, 0);
}

static __device__ inline unsigned short bin_sign(float I, float m, float s,
                                                 float g, float b) {
  // replicate reference fp32 rounding exactly: (((I-m)*s)*g)+b
  float x = __fadd_rn(__fmul_rn(__fmul_rn(__fsub_rn(I, m), s), g), b);
  return (x >= 0.0f) ? (unsigned short)0x3F80 : (unsigned short)0xBF80;
}

// --- Kernel 1: per-channel partial sums (fp64) -----------------------------
// grid (64 channels, 32 sample-groups) x 256 thr; each block: 2 samples.
__global__ __launch_bounds__(256)
void bnstats_kernel(const float* __restrict__ x_in, double* __restrict__ partials) {
  const int c = blockIdx.x, g = blockIdx.y, tid = threadIdx.x;
  double sum = 0.0, sq = 0.0;
  for (int ns = 0; ns < 2; ++ns) {
    const float4* b4 =
        (const float4*)(x_in + ((size_t)((g * 2 + ns) * C_IN + c) << 13));
#pragma unroll
    for (int j = 0; j < 8; ++j) {
      float4 v = b4[j * 256 + tid];
      double dx = v.x, dy = v.y, dz = v.z, dw = v.w;
      sum += (dx + dy) + (dz + dw);
      sq  += (dx * dx + dy * dy) + (dz * dz + dw * dw);
    }
  }
  for (int off = 32; off > 0; off >>= 1) {
    sum += __shfl_down(sum, off);
    sq  += __shfl_down(sq,  off);
  }
  __shared__ double sd[8];
  const int wv = tid >> 6;
  if ((tid & 63) == 0) { sd[wv * 2] = sum; sd[wv * 2 + 1] = sq; }
  __syncthreads();
  if (tid == 0) {
    double S = sd[0] + sd[2] + sd[4] + sd[6];
    double Q = sd[1] + sd[3] + sd[5] + sd[7];
    partials[(c * 32 + g) * 2]     = S;
    partials[(c * 32 + g) * 2 + 1] = Q;
  }
}

// --- Kernel 2: finalize packed bn params (m, s, gamma, beta) ---------------
__global__ void bnreduce_kernel(const double* __restrict__ partials,
                                const float* __restrict__ gamma,
                                const float* __restrict__ beta,
                                float4* __restrict__ bnparams) {
  const int c = threadIdx.x;
  if (c < C_IN) {
    double S = 0.0, Q = 0.0;
    for (int g = 0; g < 32; ++g) {
      S += partials[(c * 32 + g) * 2];
      Q += partials[(c * 32 + g) * 2 + 1];
    }
    const double NL = (double)N_S * (double)L_IN;  // 524288
    double mean_d = S / NL;
    float  mean_f = (float)mean_d;
    double var_d = Q / NL - 2.0 * (double)mean_f * mean_d +
                   (double)mean_f * (double)mean_f;
    float var_f = (float)var_d;
    float vpe   = __fadd_rn(var_f, 1e-5f);
    float s_f   = (float)(1.0 / sqrt((double)vpe));
    bnparams[c] = make_float4(mean_f, s_f, gamma[c], beta[c]);
  }
}

// --- Kernel 3: repack W [o][c][k] fp32 -> Wr [o][t=k*64+c] bf16 ------------
__global__ __launch_bounds__(256)
void wrepack_kernel(const float* __restrict__ W, unsigned short* __restrict__ Wr) {
  const int f = blockIdx.x * 256 + threadIdx.x;
  if (f < C_OUT * KDIM) {
    const int o = f / KDIM, rem = f - o * KDIM;
    const int c = rem / KW, k = rem - c * KW;
    unsigned int u = __builtin_bit_cast(unsigned int, W[f]);
    u += 0x7FFFu + ((u >> 16) & 1u);  // RNE to bf16
    Wr[o * KDIM + k * C_IN + c] = (unsigned short)(u >> 16);
  }
}

// --- Kernel 3b: binarize + transpose -> xbt[n][p][c] bf16, zero-padded -----
// grid (16 l-chunks, 64 samples) x 256; chunk = 512 l-positions.
__global__ __launch_bounds__(256)
void bintrans_kernel(const float* __restrict__ x_in,
                     const float4* __restrict__ bnparams,
                     unsigned short* __restrict__ xbt) {
  const int chunk = blockIdx.x, n = blockIdx.y, tid = threadIdx.x;
  const int lbase = chunk * 512;
  const int jj = tid & 127;       // float4 index within 512-l chunk
  const int half = tid >> 7;      // channel half
  const size_t xb_n = (size_t)n * XROWS * C_IN;

  // zero-pad rows (only edge chunks)
  if (chunk == 0 && tid < 48) {   // rows 0..2 : 3*128B = 48 x 8B
    ((ulonglong1*)(xbt + xb_n))[tid] = make_ulonglong1(0ull);
  }
  if (chunk == 15 && tid < 80) {  // rows 8195..8199 : 5*128B = 80 x 8B
    ((ulonglong1*)(xbt + xb_n + 8195 * C_IN))[tid] = make_ulonglong1(0ull);
  }

#pragma unroll
  for (int cc = 0; cc < 8; ++cc) {
    const int c0 = half * 32 + cc * 4;
    const float4 bp0 = bnparams[c0 + 0];
    const float4 bp1 = bnparams[c0 + 1];
    const float4 bp2 = bnparams[c0 + 2];
    const float4 bp3 = bnparams[c0 + 3];
    const int l = lbase + 4 * jj;
    const float4 f0 = ((const float4*)(x_in + ((size_t)(n * C_IN + c0 + 0) << 13)))[l >> 2];
    const float4 f1 = ((const float4*)(x_in + ((size_t)(n * C_IN + c0 + 1) << 13)))[l >> 2];
    const float4 f2 = ((const float4*)(x_in + ((size_t)(n * C_IN + c0 + 2) << 13)))[l >> 2];
    const float4 f3 = ((const float4*)(x_in + ((size_t)(n * C_IN + c0 + 3) << 13)))[l >> 2];
    const float e0[4] = {f0.x, f0.y, f0.z, f0.w};
    const float e1[4] = {f1.x, f1.y, f1.z, f1.w};
    const float e2[4] = {f2.x, f2.y, f2.z, f2.w};
    const float e3[4] = {f3.x, f3.y, f3.z, f3.w};
#pragma unroll
    for (int d = 0; d < 4; ++d) {
      ushort4 v;
      v.x = bin_sign(e0[d], bp0.x, bp0.y, bp0.z, bp0.w);
      v.y = bin_sign(e1[d], bp1.x, bp1.y, bp1.z, bp1.w);
      v.z = bin_sign(e2[d], bp2.x, bp2.y, bp2.z, bp2.w);
      v.w = bin_sign(e3[d], bp3.x, bp3.y, bp3.z, bp3.w);
      const int p = l + d + 3;
      *(ushort4*)(xbt + xb_n + (size_t)p * C_IN + c0) = v;
    }
  }
}

// --- Kernel 4 (v2): conv GEMM from xbt, no LDS, no barriers ----------------
// grid (64 l-tiles, 64 samples) x 256 (4 waves).
// wave tile 64o x 64l; block tile 128o x 128l.
__global__ __launch_bounds__(256)
void bconv2_kernel(const unsigned short* __restrict__ xbt,
                   const unsigned short* __restrict__ Wr,
                   const float* __restrict__ alpha,
                   float* __restrict__ out) {
  const int n = blockIdx.y;
  const int lbase = blockIdx.x * 128;
  const int tid = threadIdx.x;
  const int lane = tid & 63, w = tid >> 6;
  const int n16 = lane & 15, quad = lane >> 4;
  const int obase = (w & 1) * 64;
  const int lW = (w >> 1) * 64;

  fx4 acc[4][4];
#pragma unroll
  for (int ob = 0; ob < 4; ++ob)
#pragma unroll
    for (int lb = 0; lb < 4; ++lb)
      acc[ob][lb] = (fx4){0.f, 0.f, 0.f, 0.f};

  const unsigned short* arow = Wr + (obase + n16) * KDIM + quad * 8;
  const unsigned short* xrow = xbt + (size_t)n * XROWS * C_IN +
                               (size_t)(lbase + lW + n16) * C_IN + quad * 8;

#pragma unroll
  for (int ks = 0; ks < 14; ++ks) {
    const int k = ks >> 1;
    const int coff = (ks & 1) * 32;     // shorts, within-row channel offset
    s16x8 afr[4];
#pragma unroll
    for (int ob = 0; ob < 4; ++ob)
      afr[ob] = *(const s16x8*)(arow + ob * 16 * KDIM + ks * 32);
    s16x8 bfr[4];
#pragma unroll
    for (int lb = 0; lb < 4; ++lb)
      bfr[lb] = *(const s16x8*)(xrow + (size_t)(lb * 16 + k) * C_IN + coff);
#pragma unroll
    for (int ob = 0; ob < 4; ++ob)
#pragma unroll
      for (int lb = 0; lb < 4; ++lb)
        acc[ob][lb] = mfma_bf16(afr[ob], bfr[lb], acc[ob][lb]);
  }

  // epilogue: maxpool2 across adjacent lanes, *alpha, store
  float al[16];
#pragma unroll
  for (int ob = 0; ob < 4; ++ob)
#pragma unroll
    for (int r = 0; r < 4; ++r)
      al[ob * 4 + r] = alpha[obase + ob * 16 + quad * 4 + r];

  const size_t outbase = (size_t)n * C_OUT * L_OUT;
#pragma unroll
  for (int ob = 0; ob < 4; ++ob) {
#pragma unroll
    for (int lb = 0; lb < 4; ++lb) {
      const int l_local = lW + lb * 16 + n16;
#pragma unroll
      for (int r = 0; r < 4; ++r) {
        const int o = obase + ob * 16 + quad * 4 + r;
        float v  = acc[ob][lb][r];
        float pv = __shfl_xor(v, 1);
        float mx = fmaxf(v, pv);
        if ((n16 & 1) == 0) {
          out[outbase + (size_t)o * L_OUT + ((lbase + l_local) >> 1)] =
              mx * al[ob * 4 + r];
        }
      }
    }
  }
}

// --- Fallback fused kernel (round-1 path, used if ws too small) ------------
#define LT    64
#define PROWS 70
#define RS    72
__global__ __launch_bounds__(256)
void bconv_fused_kernel(const float* __restrict__ x_in,
                        const float4* __restrict__ bnparams,
                        const float* __restrict__ alpha,
                        const unsigned short* __restrict__ Wr,
                        float* __restrict__ out) {
  const int tile = blockIdx.x, n = blockIdx.y;
  const int l0 = tile * LT, tid = threadIdx.x;
  __shared__ __align__(16) unsigned short lds_xb[PROWS * RS];
  {
    const int c = tid >> 2, sub = tid & 3;
    const float4 bp = bnparams[c];
    const float* xc = x_in + ((size_t)(n * C_IN + c) << 13);
#pragma unroll
    for (int i = 0; i < 18; ++i) {
      const int p = sub * 18 + i;
      if (p < PROWS) {
        const int l = l0 + p - 3;
        unsigned short v = 0;
        if (l >= 0 && l < L_IN) v = bin_sign(xc[l], bp.x, bp.y, bp.z, bp.w);
        lds_xb[p * RS + c] = v;
      }
    }
  }
  __syncthreads();
  const int lane = tid & 63, w = tid >> 6;
  const int n16 = lane & 15, quad = lane >> 4;
  const int obase = (w & 1) * 64, lwave = (w >> 1) * 32;
  fx4 acc[4][2];
#pragma unroll
  for (int ob = 0; ob < 4; ++ob)
#pragma unroll
    for (int lb = 0; lb < 2; ++lb) acc[ob][lb] = (fx4){0.f, 0.f, 0.f, 0.f};
  const unsigned short* arow = Wr + (obase + n16) * KDIM + quad * 8;
#pragma unroll
  for (int ks = 0; ks < 14; ++ks) {
    const int k = ks >> 1, c0 = (ks & 1) * 32;
    s16x8 afr[4];
#pragma unroll
    for (int ob = 0; ob < 4; ++ob)
      afr[ob] = *(const s16x8*)(arow + ob * 16 * KDIM + ks * 32);
    s16x8 bfr[2];
#pragma unroll
    for (int lb = 0; lb < 2; ++lb) {
      const int p = lwave + lb * 16 + n16 + k;
      bfr[lb] = *(const s16x8*)(&lds_xb[p * RS + c0 + quad * 8]);
    }
#pragma unroll
    for (int ob = 0; ob < 4; ++ob)
#pragma unroll
      for (int lb = 0; lb < 2; ++lb)
        acc[ob][lb] = mfma_bf16(afr[ob], bfr[lb], acc[ob][lb]);
  }
  const size_t outbase = (size_t)n * C_OUT * L_OUT;
#pragma unroll
  for (int ob = 0; ob < 4; ++ob)
#pragma unroll
    for (int lb = 0; lb < 2; ++lb) {
      const int l_local = lwave + lb * 16 + n16;
#pragma unroll
      for (int r = 0; r < 4; ++r) {
        const int o = obase + ob * 16 + quad * 4 + r;
        float v = acc[ob][lb][r];
        float pv = __shfl_xor(v, 1);
        float mx = fmaxf(v, pv);
        if ((n16 & 1) == 0)
          out[outbase + (size_t)o * L_OUT + ((l0 + l_local) >> 1)] = mx * alpha[o];
      }
    }
}

// ---------------------------------------------------------------------------
extern "C" void kernel_launch(void* const* d_in, const int* in_sizes, int n_in,
                              void* d_out, int out_size, void* d_ws, size_t ws_size,
                              hipStream_t stream) {
  const float* x_in  = (const float*)d_in[0];
  const float* gamma = (const float*)d_in[1];
  const float* beta  = (const float*)d_in[2];
  const float* W     = (const float*)d_in[3];
  const float* alpha = (const float*)d_in[4];
  float* out = (float*)d_out;

  double*         partials = (double*)d_ws;                          // 32 KB
  float4*         bnparams = (float4*)((char*)d_ws + 32768);         // 1 KB
  unsigned short* Wr       = (unsigned short*)((char*)d_ws + 36864); // 112 KB
  unsigned short* xbt      = (unsigned short*)((char*)d_ws + 262144);
  const size_t xbt_bytes   = (size_t)N_S * XROWS * C_IN * 2;         // ~67.2 MB

  bnstats_kernel<<<dim3(64, 32), 256, 0, stream>>>(x_in, partials);
  wrepack_kernel<<<(C_OUT * KDIM + 255) / 256, 256, 0, stream>>>(W, Wr);
  bnreduce_kernel<<<1, 64, 0, stream>>>(partials, gamma, beta, bnparams);

  if (ws_size >= 262144 + xbt_bytes) {
    bintrans_kernel<<<dim3(16, 64), 256, 0, stream>>>(x_in, bnparams, xbt);
    bconv2_kernel<<<dim3(64, 64), 256, 0, stream>>>(xbt, Wr, alpha, out);
  } else {
    bconv_fused_kernel<<<dim3(128, 64), 256, 0, stream>>>(x_in, bnparams,
                                                          alpha, Wr, out);
  }
}